// Round 1
// baseline (430.274 us; speedup 1.0000x reference)
//
#include <hip/hip_runtime.h>

typedef __attribute__((ext_vector_type(8))) short short8;
typedef __attribute__((ext_vector_type(4))) float f32x4;

#define L_SEQ 2048
#define C_DIM 512
#define H_N 8
#define D_H 64
#define FF_DIM 2048

__device__ __forceinline__ unsigned short f2bf(float f) {
  unsigned int u = __float_as_uint(f);
  u = u + 0x7fffu + ((u >> 16) & 1u);
  return (unsigned short)(u >> 16);
}

// ---------- transpose + fp32->bf16 convert: out[J(n)][k] = in[k][n] ----------
__global__ __launch_bounds__(256) void transpose_conv(
    const float* __restrict__ in, unsigned short* __restrict__ out,
    int R, int Ccols, int geglu) {
  __shared__ float tile[32][33];
  int tx = threadIdx.x & 31, ty = threadIdx.x >> 5;  // ty in 0..7
  int c0 = blockIdx.x * 32, r0 = blockIdx.y * 32;
#pragma unroll
  for (int j = 0; j < 4; ++j) {
    int r = ty + j * 8;
    tile[r][tx] = in[(size_t)(r0 + r) * Ccols + c0 + tx];
  }
  __syncthreads();
#pragma unroll
  for (int j = 0; j < 4; ++j) {
    int rr = ty + j * 8;
    int n = c0 + rr;  // input col = output row (pre-remap)
    int J = n;
    if (geglu) {
      int hc = Ccols >> 1;
      J = (n < hc) ? (((n >> 4) << 5) + (n & 15))
                   : ((((n - hc) >> 4) << 5) + 16 + ((n - hc) & 15));
    }
    out[(size_t)J * R + r0 + tx] = f2bf(tile[tx][rr]);
  }
}

// ---------- LayerNorm fp32 -> bf16 (one wave per row, C=512) ----------
__global__ __launch_bounds__(256) void ln_kernel(
    const float* __restrict__ in, const float* __restrict__ g,
    const float* __restrict__ b, unsigned short* __restrict__ out) {
  int w = threadIdx.x >> 6, lane = threadIdx.x & 63;
  int row = blockIdx.x * 4 + w;
  const float4* p = (const float4*)(in + (size_t)row * C_DIM);
  float4 v0 = p[lane * 2], v1 = p[lane * 2 + 1];
  float s = v0.x + v0.y + v0.z + v0.w + v1.x + v1.y + v1.z + v1.w;
  float q = v0.x * v0.x + v0.y * v0.y + v0.z * v0.z + v0.w * v0.w +
            v1.x * v1.x + v1.y * v1.y + v1.z * v1.z + v1.w * v1.w;
#pragma unroll
  for (int m = 1; m < 64; m <<= 1) {
    s += __shfl_xor(s, m);
    q += __shfl_xor(q, m);
  }
  float mean = s * (1.0f / 512.0f);
  float var = q * (1.0f / 512.0f) - mean * mean;
  float rstd = rsqrtf(var + 1e-5f);
  const float4* gp = (const float4*)g;
  const float4* bp = (const float4*)b;
  float4 g0 = gp[lane * 2], g1 = gp[lane * 2 + 1];
  float4 b0 = bp[lane * 2], b1 = bp[lane * 2 + 1];
  short8 o;
  o[0] = (short)f2bf((v0.x - mean) * rstd * g0.x + b0.x);
  o[1] = (short)f2bf((v0.y - mean) * rstd * g0.y + b0.y);
  o[2] = (short)f2bf((v0.z - mean) * rstd * g0.z + b0.z);
  o[3] = (short)f2bf((v0.w - mean) * rstd * g0.w + b0.w);
  o[4] = (short)f2bf((v1.x - mean) * rstd * g1.x + b1.x);
  o[5] = (short)f2bf((v1.y - mean) * rstd * g1.y + b1.y);
  o[6] = (short)f2bf((v1.z - mean) * rstd * g1.z + b1.z);
  o[7] = (short)f2bf((v1.w - mean) * rstd * g1.w + b1.w);
  *((short8*)(out + (size_t)row * C_DIM) + lane) = o;
}

// ---------- GEMM: C[M,N] = A[M,K] @ Bt[N,K]^T (+epilogue) ----------
// EPI 0: QKV -> bf16 [3][n,h,l,d] (+bq/bk/bv)
// EPI 1: GEGLU (interleaved 16u/16g cols) -> y bf16 [M, 2048] (+bp)
// EPI 2: out fp32 = acc + b2 + resid
template <int EPI>
__global__ __launch_bounds__(256, 2) void gemm_kernel(
    const unsigned short* __restrict__ A, const unsigned short* __restrict__ Bt,
    int M, int N, int K,
    const float* __restrict__ bias0, const float* __restrict__ bias1,
    const float* __restrict__ bias2, const float* __restrict__ resid,
    void* __restrict__ outp) {
  __shared__ unsigned short As[128][40];
  __shared__ unsigned short Bs[128][40];
  int tid = threadIdx.x;
  int lane = tid & 63, w = tid >> 6;
  int wr = w >> 1, wc = w & 1;
  int hi = lane >> 4, l15 = lane & 15;
  int m0 = blockIdx.y * 128, n0 = blockIdx.x * 128;
  int srow = tid >> 2, scol = (tid & 3) * 8;

  f32x4 acc[4][4];
#pragma unroll
  for (int i = 0; i < 4; ++i)
#pragma unroll
    for (int j = 0; j < 4; ++j) acc[i][j] = (f32x4){0.f, 0.f, 0.f, 0.f};

  const size_t aBase = (size_t)(m0 + srow) * K + scol;
  const size_t bBase = (size_t)(n0 + srow) * K + scol;

  for (int k0 = 0; k0 < K; k0 += 32) {
    short8 a0 = *(const short8*)(A + aBase + k0);
    short8 a1 = *(const short8*)(A + aBase + (size_t)64 * K + k0);
    short8 b0 = *(const short8*)(Bt + bBase + k0);
    short8 b1 = *(const short8*)(Bt + bBase + (size_t)64 * K + k0);
    __syncthreads();
    *(short8*)&As[srow][scol] = a0;
    *(short8*)&As[srow + 64][scol] = a1;
    *(short8*)&Bs[srow][scol] = b0;
    *(short8*)&Bs[srow + 64][scol] = b1;
    __syncthreads();
    short8 af[4], bf[4];
#pragma unroll
    for (int mi = 0; mi < 4; ++mi)
      af[mi] = *(const short8*)&As[wr * 64 + mi * 16 + l15][hi * 8];
#pragma unroll
    for (int ni = 0; ni < 4; ++ni)
      bf[ni] = *(const short8*)&Bs[wc * 64 + ni * 16 + l15][hi * 8];
#pragma unroll
    for (int mi = 0; mi < 4; ++mi)
#pragma unroll
      for (int ni = 0; ni < 4; ++ni)
        acc[mi][ni] = __builtin_amdgcn_mfma_f32_16x16x32_bf16(
            af[mi], bf[ni], acc[mi][ni], 0, 0, 0);
  }

  if (EPI == 0) {
    unsigned short* out = (unsigned short*)outp;
#pragma unroll
    for (int mi = 0; mi < 4; ++mi) {
#pragma unroll
      for (int ni = 0; ni < 4; ++ni) {
        int col = n0 + wc * 64 + ni * 16 + l15;
        int t = col >> 9, jj = col & 511;
        int h = jj >> 6, d = jj & 63;
        const float* bptr = (t == 0) ? bias0 : (t == 1 ? bias1 : bias2);
        float bv = bptr[jj];
        int rbase = m0 + wr * 64 + mi * 16 + hi * 4;
#pragma unroll
        for (int i = 0; i < 4; ++i) {
          int m = rbase + i;
          int n = m >> 11, l = m & 2047;
          size_t dst =
              (size_t)t * 4194304u + (((size_t)(n * H_N + h)) * L_SEQ + l) * D_H + d;
          out[dst] = f2bf(acc[mi][ni][i] + bv);
        }
      }
    }
  } else if (EPI == 1) {
    unsigned short* out = (unsigned short*)outp;
#pragma unroll
    for (int mi = 0; mi < 4; ++mi) {
#pragma unroll
      for (int np = 0; np < 2; ++np) {
        int J16 = (n0 >> 4) + wc * 4 + np * 2;  // even
        int ucol = (J16 >> 1) * 16 + l15;       // real u column in [0,2048)
        float bu = bias0[ucol], bg = bias0[2048 + ucol];
        int rbase = m0 + wr * 64 + mi * 16 + hi * 4;
#pragma unroll
        for (int i = 0; i < 4; ++i) {
          float uu = acc[mi][np * 2][i] + bu;
          float gg = acc[mi][np * 2 + 1][i] + bg;
          float ge = 0.5f * gg * (1.0f + erff(gg * 0.70710678118f));
          out[(size_t)(rbase + i) * FF_DIM + ucol] = f2bf(uu * ge);
        }
      }
    }
  } else {
    float* out = (float*)outp;
#pragma unroll
    for (int mi = 0; mi < 4; ++mi) {
#pragma unroll
      for (int ni = 0; ni < 4; ++ni) {
        int col = n0 + wc * 64 + ni * 16 + l15;
        float bv = bias0[col];
        int rbase = m0 + wr * 64 + mi * 16 + hi * 4;
#pragma unroll
        for (int i = 0; i < 4; ++i) {
          size_t idx = (size_t)(rbase + i) * C_DIM + col;
          out[idx] = acc[mi][ni][i] + bv + resid[idx];
        }
      }
    }
  }
}

// ---------- flash attention, fuses x1 = x + attn_out ----------
__global__ __launch_bounds__(256, 2) void attn_kernel(
    const unsigned short* __restrict__ qkv, const float* __restrict__ x,
    float* __restrict__ x1) {
  __shared__ unsigned short Kt[32][72];
  __shared__ unsigned short Vt[64][40];
  __shared__ unsigned short Pt[4][16][40];
  int tid = threadIdx.x, lane = tid & 63, w = tid >> 6;
  int hi = lane >> 4, l15 = lane & 15;
  int nh = blockIdx.y;
  int n = nh >> 3, h = nh & 7;
  int q0 = blockIdx.x * 64;
  const unsigned short* qb = qkv + (size_t)nh * L_SEQ * D_H;
  const unsigned short* kb = qb + (size_t)4 * H_N * L_SEQ * D_H;
  const unsigned short* vb = kb + (size_t)4 * H_N * L_SEQ * D_H;

  short8 qf0 = *(const short8*)(qb + (size_t)(q0 + w * 16 + l15) * D_H + hi * 8);
  short8 qf1 =
      *(const short8*)(qb + (size_t)(q0 + w * 16 + l15) * D_H + 32 + hi * 8);

  f32x4 o[4];
#pragma unroll
  for (int c = 0; c < 4; ++c) o[c] = (f32x4){0.f, 0.f, 0.f, 0.f};
  float mrow[4] = {-1e30f, -1e30f, -1e30f, -1e30f};
  float lrow[4] = {0.f, 0.f, 0.f, 0.f};

  int stok = tid >> 3, sd = (tid & 7) * 8;
  for (int t0 = 0; t0 < L_SEQ; t0 += 32) {
    short8 kv = *(const short8*)(kb + (size_t)(t0 + stok) * D_H + sd);
    short8 vv = *(const short8*)(vb + (size_t)(t0 + stok) * D_H + sd);
    __syncthreads();
    *(short8*)&Kt[stok][sd] = kv;
#pragma unroll
    for (int j = 0; j < 8; ++j) Vt[sd + j][stok] = (unsigned short)vv[j];
    __syncthreads();

    f32x4 sc[2];
#pragma unroll
    for (int mc = 0; mc < 2; ++mc) {
      f32x4 s = (f32x4){0.f, 0.f, 0.f, 0.f};
      short8 kf0 = *(const short8*)&Kt[mc * 16 + l15][hi * 8];
      short8 kf1 = *(const short8*)&Kt[mc * 16 + l15][32 + hi * 8];
      s = __builtin_amdgcn_mfma_f32_16x16x32_bf16(qf0, kf0, s, 0, 0, 0);
      s = __builtin_amdgcn_mfma_f32_16x16x32_bf16(qf1, kf1, s, 0, 0, 0);
      sc[mc] = s;
    }
#pragma unroll
    for (int i = 0; i < 4; ++i) {
      float s0 = sc[0][i] * 0.125f, s1 = sc[1][i] * 0.125f;
      float t = fmaxf(s0, s1);
      t = fmaxf(t, __shfl_xor(t, 1));
      t = fmaxf(t, __shfl_xor(t, 2));
      t = fmaxf(t, __shfl_xor(t, 4));
      t = fmaxf(t, __shfl_xor(t, 8));
      float mnew = fmaxf(mrow[i], t);
      float scale = __expf(mrow[i] - mnew);
      float p0 = __expf(s0 - mnew), p1 = __expf(s1 - mnew);
      float ps = p0 + p1;
      ps += __shfl_xor(ps, 1);
      ps += __shfl_xor(ps, 2);
      ps += __shfl_xor(ps, 4);
      ps += __shfl_xor(ps, 8);
      lrow[i] = lrow[i] * scale + ps;
      mrow[i] = mnew;
      o[0][i] *= scale;
      o[1][i] *= scale;
      o[2][i] *= scale;
      o[3][i] *= scale;
      Pt[w][hi * 4 + i][l15] = f2bf(p0);
      Pt[w][hi * 4 + i][l15 + 16] = f2bf(p1);
    }
    short8 pf = *(const short8*)&Pt[w][l15][hi * 8];
#pragma unroll
    for (int c = 0; c < 4; ++c) {
      short8 vf = *(const short8*)&Vt[c * 16 + l15][hi * 8];
      o[c] = __builtin_amdgcn_mfma_f32_16x16x32_bf16(pf, vf, o[c], 0, 0, 0);
    }
  }
  float inv[4];
#pragma unroll
  for (int i = 0; i < 4; ++i) inv[i] = 1.0f / lrow[i];
#pragma unroll
  for (int c = 0; c < 4; ++c)
#pragma unroll
    for (int i = 0; i < 4; ++i) {
      int tok = q0 + w * 16 + hi * 4 + i;
      size_t idx = ((size_t)(n * L_SEQ + tok)) * C_DIM + h * 64 + c * 16 + l15;
      x1[idx] = x[idx] + o[c][i] * inv[i];
    }
}

extern "C" void kernel_launch(void* const* d_in, const int* in_sizes, int n_in,
                              void* d_out, int out_size, void* d_ws,
                              size_t ws_size, hipStream_t stream) {
  const float* x = (const float*)d_in[0];
  const float* ln0g = (const float*)d_in[1];
  const float* ln0b = (const float*)d_in[2];
  const float* Wq = (const float*)d_in[3];
  const float* bq = (const float*)d_in[4];
  const float* Wk = (const float*)d_in[5];
  const float* bk = (const float*)d_in[6];
  const float* Wv = (const float*)d_in[7];
  const float* bv = (const float*)d_in[8];
  const float* ln1g = (const float*)d_in[9];
  const float* ln1b = (const float*)d_in[10];
  const float* Wp = (const float*)d_in[11];
  const float* bp = (const float*)d_in[12];
  const float* W2 = (const float*)d_in[13];
  const float* b2 = (const float*)d_in[14];

  char* ws = (char*)d_ws;
  unsigned short* hbuf = (unsigned short*)ws;                // 8192*512 bf16
  unsigned short* qkvb = (unsigned short*)(ws + 8388608);    // 3*4194304 bf16
  unsigned short* ybuf = (unsigned short*)ws;                // 8192*2048 bf16 (reuse)
  float* x1 = (float*)(ws + 33554432);                       // 8192*512 f32
  unsigned short* h2 = (unsigned short*)(ws + 33554432 + 16777216);
  unsigned short* wqkvt = (unsigned short*)(ws + 33554432 + 16777216 + 8388608);
  unsigned short* wpt = wqkvt + 1536 * 512;
  unsigned short* w2t = wpt + 4096 * 512;

  transpose_conv<<<dim3(16, 16), 256, 0, stream>>>(Wq, wqkvt, 512, 512, 0);
  transpose_conv<<<dim3(16, 16), 256, 0, stream>>>(Wk, wqkvt + 262144, 512, 512, 0);
  transpose_conv<<<dim3(16, 16), 256, 0, stream>>>(Wv, wqkvt + 524288, 512, 512, 0);
  transpose_conv<<<dim3(128, 16), 256, 0, stream>>>(Wp, wpt, 512, 4096, 1);
  transpose_conv<<<dim3(16, 64), 256, 0, stream>>>(W2, w2t, 2048, 512, 0);

  ln_kernel<<<2048, 256, 0, stream>>>(x, ln0g, ln0b, hbuf);
  gemm_kernel<0><<<dim3(12, 64), 256, 0, stream>>>(hbuf, wqkvt, 8192, 1536, 512,
                                                   bq, bk, bv, nullptr, qkvb);
  attn_kernel<<<dim3(32, 32), 256, 0, stream>>>(qkvb, x, x1);
  ln_kernel<<<2048, 256, 0, stream>>>(x1, ln1g, ln1b, h2);
  gemm_kernel<1><<<dim3(32, 64), 256, 0, stream>>>(h2, wpt, 8192, 4096, 512, bp,
                                                   nullptr, nullptr, nullptr, ybuf);
  gemm_kernel<2><<<dim3(4, 64), 256, 0, stream>>>(ybuf, w2t, 8192, 512, 2048, b2,
                                                  nullptr, nullptr, x1,
                                                  (float*)d_out);
}